// Round 1
// baseline (83.101 us; speedup 1.0000x reference)
//
#include <hip/hip_runtime.h>

#define PNUM 512
#define LB_BLOCKS 512   // L_PREDS * BATCH = 2 * 256

// Kernel 1: one block per (l, b) pair. 512 threads, thread t owns shift i = t.
// Computes min_i sum_j [ sl1(px[j]-gx[(i+j)%512]) + sl1(py[j]-gy[(i+j)%512]) ]
// (raw sum over j; the /512 mean and the /512 batch*L average are applied in kernel 2).
__global__ __launch_bounds__(512)
void poly_match_kernel(const float* __restrict__ pred,   // (2,256,512,2)
                       const float* __restrict__ gt,     // (256,512,2)
                       float* __restrict__ block_min)    // (512,)
{
    __shared__ float2 sp[PNUM];        // pred tile   (4 KB)
    __shared__ float2 sg2[2 * PNUM];   // gt doubled  (8 KB) -> no (i+j)%512 wrap
    __shared__ float swave[8];

    const int bid = blockIdx.x;        // bid = l*256 + b
    const int b   = bid & 255;
    const int t   = threadIdx.x;

    const float2* pp = (const float2*)(pred + (size_t)bid * PNUM * 2);
    const float2* gp = (const float2*)(gt   + (size_t)b   * PNUM * 2);

    float2 g = gp[t];
    sp[t]          = pp[t];
    sg2[t]         = g;
    sg2[t + PNUM]  = g;
    __syncthreads();

    const int i = t;
    float acc = 0.0f;

    #pragma unroll 8
    for (int j = 0; j < PNUM; ++j) {
        float2 p  = sp[j];          // wave-uniform broadcast
        float2 gg = sg2[i + j];     // consecutive lanes -> consecutive entries
        float dx = p.x - gg.x;
        float dy = p.y - gg.y;
        float ax = fabsf(dx);
        float ay = fabsf(dy);
        // smooth_l1(x) = t*(|x| - 0.5*t), t = min(|x|, 1)
        float tx = fminf(ax, 1.0f);
        float ty = fminf(ay, 1.0f);
        acc = fmaf(tx, fmaf(-0.5f, tx, ax), acc);
        acc = fmaf(ty, fmaf(-0.5f, ty, ay), acc);
    }

    // min-reduce across the block (wave64 shuffle, then 8 wave leaders via LDS)
    float m = acc;
    #pragma unroll
    for (int d = 1; d < 64; d <<= 1)
        m = fminf(m, __shfl_xor(m, d, 64));

    const int lane = t & 63;
    const int w    = t >> 6;
    if (lane == 0) swave[w] = m;
    __syncthreads();
    if (t == 0) {
        float mm = swave[0];
        #pragma unroll
        for (int k = 1; k < 8; ++k) mm = fminf(mm, swave[k]);
        block_min[bid] = mm;
    }
}

// Kernel 2: deterministic reduction of the 512 per-(l,b) mins.
// loss = sum(block_min) / (PNUM * L*B) = sum / (512 * 512)
__global__ __launch_bounds__(512)
void poly_match_finalize(const float* __restrict__ block_min,
                         float* __restrict__ out)
{
    const int t = threadIdx.x;
    float v = block_min[t];
    #pragma unroll
    for (int d = 1; d < 64; d <<= 1)
        v += __shfl_xor(v, d, 64);

    __shared__ float s[8];
    if ((t & 63) == 0) s[t >> 6] = v;
    __syncthreads();
    if (t == 0) {
        float tot = 0.0f;
        #pragma unroll
        for (int k = 0; k < 8; ++k) tot += s[k];
        out[0] = tot * (1.0f / (512.0f * 512.0f));
    }
}

extern "C" void kernel_launch(void* const* d_in, const int* in_sizes, int n_in,
                              void* d_out, int out_size, void* d_ws, size_t ws_size,
                              hipStream_t stream)
{
    const float* pred = (const float*)d_in[0];  // (2,256,512,2) fp32
    const float* gt   = (const float*)d_in[1];  // (256,512,2)   fp32
    float* out  = (float*)d_out;                // scalar fp32
    float* bmin = (float*)d_ws;                 // 512 floats of scratch

    poly_match_kernel<<<LB_BLOCKS, PNUM, 0, stream>>>(pred, gt, bmin);
    poly_match_finalize<<<1, PNUM, 0, stream>>>(bmin, out);
}